// Round 11
// baseline (336.705 us; speedup 1.0000x reference)
//
#include <hip/hip_runtime.h>

// GCN: h1 = relu(Agg(x@W1) + b1); h2 = Agg(h1@W2) + b2; out = h2@Wc + bc
// Agg = symmetric-normalized adjacency with self-loops (PyG GCNConv).
// R11: feature-sliced gathers. A 32-feature slice of hw (N*32*2B = 3.2MB)
// fits a per-XCD L2 (4MiB), so the ~16x random row reuse hits L2 instead of
// L3/HBM. Phase encoded in blockIdx (single launch): blocks [p*G,(p+1)*G)
// process feature slice p. Slot geometry: 4 lanes x 16B = one 64B line per
// edge; 16 edge slots per wave (16 lines in flight).
// R10 carried: tile MFMA GEMMs (coalesced LDS A-stage, global-read B-frags),
// XCD-partitioned hist/fill, 1-kernel scan.

#define DIN 128
#define HID 128
#define FOUT 64

using half8 = __attribute__((ext_vector_type(8))) _Float16;
using float8 = __attribute__((ext_vector_type(8))) float;
using f32x4 = __attribute__((ext_vector_type(4))) float;

// Deterministic dst->partition map (pure function; locality heuristic only).
__device__ inline int part_of(int d, float invn) {
  int p = (int)((float)d * invn);
  return p > 7 ? 7 : p;
}

// Partitioned histogram: block b = chunk (b>>3) x partition (b&7).
__global__ __launch_bounds__(256) void hist_kernel(
    const int* __restrict__ ei, int E, int* __restrict__ counts, float invn) {
  int part = blockIdx.x & 7;
  int e = (blockIdx.x >> 3) * 256 + threadIdx.x;
  if (e >= E) return;
  int d = ei[E + e];
  if (part_of(d, invn) == part) atomicAdd(&counts[d], 1);
}

// One-kernel scan: block b computes base = sum counts[0..b*256) directly
// (coalesced strided read), local-scans its 256 chunk, fused node_init.
__global__ __launch_bounds__(256) void scan_fused_kernel(
    const int* __restrict__ counts, int N, int E, int* __restrict__ offsets,
    int* __restrict__ cursor, float* __restrict__ dis) {
  int t = threadIdx.x;
  int start = blockIdx.x * 256;

  int partial = 0;
  for (int i = t; i < start; i += 256) partial += counts[i];
#pragma unroll
  for (int off = 32; off > 0; off >>= 1)
    partial += __shfl_down(partial, off, 64);
  __shared__ int red[4];
  if ((t & 63) == 0) red[t >> 6] = partial;
  __syncthreads();
  int base = red[0] + red[1] + red[2] + red[3];

  int i = start + t;
  int c = (i < N) ? counts[i] : 0;
  __shared__ int s[256];
  s[t] = c;
  __syncthreads();
  for (int off = 1; off < 256; off <<= 1) {
    int u = 0;
    if (t >= off) u = s[t - off];
    __syncthreads();
    s[t] += u;
    __syncthreads();
  }
  int excl = s[t] - c + base;
  if (i < N) {
    offsets[i] = excl;
    cursor[i] = excl;
    dis[i] = rsqrtf((float)c + 1.0f);  // deg includes self-loop
  }
  if (i == N - 1) offsets[N] = E;
}

// Partitioned fill: only XCD (blockIdx&7) writes partition's csr/cursor range.
__global__ __launch_bounds__(256) void fill_kernel(
    const int* __restrict__ ei, int E, int* __restrict__ cursor,
    int* __restrict__ csr, float invn) {
  int part = blockIdx.x & 7;
  int e = (blockIdx.x >> 3) * 256 + threadIdx.x;
  if (e >= E) return;
  int d = ei[E + e];
  if (part_of(d, invn) != part) return;
  int s = ei[e];
  int p = atomicAdd(&cursor[d], 1);
  csr[p] = s;
}

// Tile MFMA GEMM: C[M x NCOL] = A[M x K] @ W[K x NCOL](fp32), fp16 compute,
// fp32 accumulate. One 64-row tile per block.
// AH: A fp16 (else fp32, converted during staging).
// H16: store fp16 (gather operand; *dis[row] if SCALE); else fp32 + bias.
template <int K, int NCOL, bool AH, bool H16, bool SCALE>
__global__ __launch_bounds__(256) void gemm_tile_kernel(
    const void* __restrict__ A, const float* __restrict__ W,
    const float* __restrict__ dis, const float* __restrict__ bias,
    void* __restrict__ Cout, int M) {
  constexpr int KP = K + 8;     // halfs; (K+8)*2 B is a 16B multiple
  constexpr int KS = K / 32;    // k-steps
  constexpr int G8 = K / 8;     // half8 groups per row
  constexpr int NW = NCOL / 4;  // cols per wave
  constexpr int CT = NW / 16;   // 16-col tiles per wave
  __shared__ _Float16 As[64 * KP];

  int tid = threadIdx.x;
  int r0 = blockIdx.x * 64;

  // stage A tile (64 x K) -> fp16 LDS, coalesced global reads
  for (int g = tid; g < 64 * G8; g += 256) {
    int row = g / G8, c8 = g % G8;
    half8 h = (half8)(_Float16)0;
    if (r0 + row < M) {
      if (AH) {
        h = *(const half8*)((const _Float16*)A + (size_t)(r0 + row) * K +
                            c8 * 8);
      } else {
        const float* ap = (const float*)A + (size_t)(r0 + row) * K + c8 * 8;
        float4 a0 = *(const float4*)ap;
        float4 a1 = *(const float4*)(ap + 4);
        h[0] = (_Float16)a0.x; h[1] = (_Float16)a0.y;
        h[2] = (_Float16)a0.z; h[3] = (_Float16)a0.w;
        h[4] = (_Float16)a1.x; h[5] = (_Float16)a1.y;
        h[6] = (_Float16)a1.z; h[7] = (_Float16)a1.w;
      }
    }
    *(half8*)&As[row * KP + c8 * 8] = h;
  }

  int wave = tid >> 6, lane = tid & 63;
  int m = lane & 15, quad = lane >> 4;
  int cw = wave * NW;

  // B fragments: B[k=quad*8+j][n=cw+ct*16+m] via scalar global loads of W
  // (coalesced across m within each quad; W is <=64KB, L2-resident).
  half8 b[CT][KS];
#pragma unroll
  for (int ct = 0; ct < CT; ++ct) {
    int n = cw + ct * 16 + m;
#pragma unroll
    for (int s = 0; s < KS; ++s) {
#pragma unroll
      for (int j = 0; j < 8; ++j)
        b[ct][s][j] = (_Float16)W[(size_t)(s * 32 + quad * 8 + j) * NCOL + n];
    }
  }

  float bval[CT];
#pragma unroll
  for (int ct = 0; ct < CT; ++ct)
    bval[ct] = H16 ? 0.f : bias[cw + ct * 16 + m];

  __syncthreads();

  f32x4 acc[4][CT];
#pragma unroll
  for (int rt = 0; rt < 4; ++rt)
#pragma unroll
    for (int ct = 0; ct < CT; ++ct) acc[rt][ct] = (f32x4){0.f, 0.f, 0.f, 0.f};

#pragma unroll
  for (int rt = 0; rt < 4; ++rt) {
#pragma unroll
    for (int s = 0; s < KS; ++s) {
      half8 af = *(half8*)&As[(rt * 16 + m) * KP + s * 32 + quad * 8];
#pragma unroll
      for (int ct = 0; ct < CT; ++ct)
        acc[rt][ct] = __builtin_amdgcn_mfma_f32_16x16x32_f16(
            af, b[ct][s], acc[rt][ct], 0, 0, 0);
    }
  }

  // epilogue: C col = cw+ct*16+m, row = r0+rt*16+quad*4+i
#pragma unroll
  for (int rt = 0; rt < 4; ++rt) {
#pragma unroll
    for (int i = 0; i < 4; ++i) {
      int row = r0 + rt * 16 + quad * 4 + i;
      if (row >= M) continue;
      if (H16) {
        float d = SCALE ? dis[row] : 1.0f;
#pragma unroll
        for (int ct = 0; ct < CT; ++ct)
          ((_Float16*)Cout)[(size_t)row * NCOL + cw + ct * 16 + m] =
              (_Float16)(acc[rt][ct][i] * d);
      } else {
#pragma unroll
        for (int ct = 0; ct < CT; ++ct)
          ((float*)Cout)[(size_t)row * NCOL + cw + ct * 16 + m] =
              acc[rt][ct][i] + bval[ct];
      }
    }
  }
}

// Feature-sliced gather segment-sum, one node-slice per wave.
// Slice = 32 features: 4 lanes x half8 per edge slot (one 64B line),
// 16 edge slots per wave. Phase p = blockIdx.x / G covers features
// [p*32,(p+1)*32); slice working set fits per-XCD L2.
// PRESCALED: rows already carry dis[src] (skip per-edge dis load).
// RELU + fp16 out (layer 1) vs fp32 + bias out (layer 2) via HOUT.
template <int F, bool PRESCALED, bool RELU, bool HOUT>
__global__ __launch_bounds__(256) void gather_slice_kernel(
    const _Float16* __restrict__ hw, const float* __restrict__ dis,
    const int* __restrict__ off, const int* __restrict__ csr,
    const float* __restrict__ bias, void* __restrict__ out, int N, int G) {
  constexpr int SL = 32;        // slice width
  constexpr int FC = SL / 8;    // 4 lanes per edge slot
  constexpr int EPW = 64 / FC;  // 16 edge slots per wave
  int phase = blockIdx.x / G;
  int chunk = blockIdx.x - phase * G;
  int wave = threadIdx.x >> 6;
  int lane = threadIdx.x & 63;
  int eslot = lane / FC;  // 0..15
  int c = lane % FC;      // 0..3
  int n = chunk * 4 + wave;
  if (n >= N) return;
  int fb = phase * SL;  // feature base of this slice

  float dn = dis[n];
  float8 acc = {0.f, 0.f, 0.f, 0.f, 0.f, 0.f, 0.f, 0.f};
  if (eslot == 0) {  // self loop
    half8 v = *(const half8*)(hw + (size_t)n * F + fb + c * 8);
    acc = __builtin_convertvector(v, float8);
    if (!PRESCALED) acc *= dn;  // outer *dn below gives dn^2
  }

  int j0 = off[n], j1 = off[n + 1];
  for (int j = j0 + eslot; j < j1; j += EPW) {
    int s = csr[j];
    half8 v = *(const half8*)(hw + (size_t)s * F + fb + c * 8);
    if (PRESCALED)
      acc += __builtin_convertvector(v, float8);
    else
      acc += __builtin_convertvector(v, float8) * dis[s];
  }

  // fold edge slots: strides 4,8,16,32
#pragma unroll
  for (int st = FC; st < 64; st <<= 1) {
#pragma unroll
    for (int i = 0; i < 8; ++i) acc[i] += __shfl_xor(acc[i], st, 64);
  }

  if (eslot == 0) {
    if (HOUT) {  // fp16 out (+relu): layer 1
      half8 h;
#pragma unroll
      for (int i = 0; i < 8; ++i) {
        float v = fmaf(acc[i], dn, bias[fb + c * 8 + i]);
        h[i] = (_Float16)(RELU ? fmaxf(v, 0.f) : v);
      }
      *(half8*)((_Float16*)out + (size_t)n * F + fb + c * 8) = h;
    } else {  // fp32 out: layer 2 (output 0)
      float4 b0 = *(const float4*)&bias[fb + c * 8 + 0];
      float4 b1 = *(const float4*)&bias[fb + c * 8 + 4];
      float4 r0 = make_float4(fmaf(acc[0], dn, b0.x), fmaf(acc[1], dn, b0.y),
                              fmaf(acc[2], dn, b0.z), fmaf(acc[3], dn, b0.w));
      float4 r1 = make_float4(fmaf(acc[4], dn, b1.x), fmaf(acc[5], dn, b1.y),
                              fmaf(acc[6], dn, b1.z), fmaf(acc[7], dn, b1.w));
      float* op = (float*)out + (size_t)n * F + fb + c * 8;
      *(float4*)(op + 0) = r0;
      *(float4*)(op + 4) = r1;
    }
  }
}

extern "C" void kernel_launch(void* const* d_in, const int* in_sizes, int n_in,
                              void* d_out, int out_size, void* d_ws,
                              size_t ws_size, hipStream_t stream) {
  const float* x = (const float*)d_in[0];
  const int* ei = (const int*)d_in[1];
  const float* W1 = (const float*)d_in[2];
  const float* b1 = (const float*)d_in[3];
  const float* W2 = (const float*)d_in[4];
  const float* b2 = (const float*)d_in[5];
  const float* Wc = (const float*)d_in[6];
  const float* bc = (const float*)d_in[7];

  int N = in_sizes[0] / DIN;
  int E = in_sizes[1] / 2;
  int nper = (N + 7) / 8;           // dst-range partition size
  float invn = 1.0f / (float)nper;  // deterministic partition map scale

  char* w = (char*)d_ws;
  size_t off = 0;
  auto alloc = [&](size_t bytes) {
    char* p = w + off;
    off += (bytes + 255) & ~(size_t)255;
    return p;
  };
  int* counts = (int*)alloc((size_t)N * 4);
  int* offsets = (int*)alloc((size_t)(N + 1) * 4);
  int* cursor = (int*)alloc((size_t)N * 4);
  int* csr = (int*)alloc((size_t)E * 4);
  float* dis = (float*)alloc((size_t)N * 4);
  _Float16* hw1 = (_Float16*)alloc((size_t)N * DIN * 2);  // fp16, UNscaled
  _Float16* h1 = (_Float16*)alloc((size_t)N * HID * 2);   // fp16
  _Float16* hw2 = hw1;  // alias: hw1 dead after gather1

  float* out_h2 = (float*)d_out;             // output 0: h2 [N x 64]
  float* out_y = out_h2 + (size_t)N * FOUT;  // output 1: out [N x 64]

  hipMemsetAsync(counts, 0, (size_t)N * 4, stream);

  int egrid = (E + 255) / 256;
  int ngrid = (N + 255) / 256;
  int G = (N + 3) / 4;        // gather: 4 node-slices (waves) per block
  int tgrid = (N + 63) / 64;  // gemm: one 64-row tile per block

  hist_kernel<<<egrid * 8, 256, 0, stream>>>(ei, E, counts, invn);
  scan_fused_kernel<<<ngrid, 256, 0, stream>>>(counts, N, E, offsets, cursor,
                                               dis);
  fill_kernel<<<egrid * 8, 256, 0, stream>>>(ei, E, cursor, csr, invn);

  // layer 1: hw1 = x @ W1 (fp16, unscaled)
  gemm_tile_kernel<DIN, HID, false, true, false><<<tgrid, 256, 0, stream>>>(
      x, W1, nullptr, nullptr, hw1, N);
  // h1 = relu(dn*Agg(hw1*ds) + b1) (fp16); 4 feature slices via blockIdx
  gather_slice_kernel<HID, false, true, true><<<4 * G, 256, 0, stream>>>(
      hw1, dis, offsets, csr, b1, h1, N, G);

  // hw2 = (h1 @ W2)*dis (fp16) ; h2 = dn*Agg(hw2) + b2 -> out_h2 (2 slices)
  gemm_tile_kernel<HID, FOUT, true, true, true><<<tgrid, 256, 0, stream>>>(
      h1, W2, dis, nullptr, hw2, N);
  gather_slice_kernel<FOUT, true, false, false><<<2 * G, 256, 0, stream>>>(
      hw2, dis, offsets, csr, b2, out_h2, N, G);

  // head: out_y = h2 @ Wc + bc (fp32 h2 from d_out, streaming tile MFMA)
  gemm_tile_kernel<FOUT, FOUT, false, false, false><<<tgrid, 256, 0, stream>>>(
      out_h2, Wc, nullptr, bc, out_y, N);
}